// Round 2
// baseline (7872.292 us; speedup 1.0000x reference)
//
#include <hip/hip_runtime.h>
#include <hip/hip_bf16.h>
#include <math.h>

// MDN-RNN: B=128, T=512, Z=32, A=3, H=256, K=5, IN=35, 4H=1024, MDN=325
#define T_LEN 512
#define B_SZ  128
#define H_DIM 256
#define G_DIM 1024
#define IN_D  35
#define MDN_D 325
#define K_MIX 5

#define NGROUP 8     // batch groups
#define NSLICE 32    // gate-dim slices  (NGROUP*NSLICE = 256 blocks = 1/CU)
#define GB     16    // batches per group
#define SC     32    // gate cols per slice (8 h-cols x 4 gates)

// d_out layout: log_pi[B,T,5] | mu[B,T,5,32] | sigma[B,T,5,32] | c[B,256] | h[B,256]
static constexpr long OFF_MU    = 327680L;
static constexpr long OFF_SIGMA = 10813440L;
static constexpr long OFF_C     = 21299200L;
static constexpr long OFF_H     = 21331968L;

// ws layout (total ~33.83 MB, proven ws_size >= 64 MB)
static constexpr size_t WS_OUT_BF16 = 0;                    // B*T*H bf16 = 33,554,432 B
static constexpr size_t WS_HGLB     = 33554432;             // 8 grp * 2 buf * 16 b * 256 f32
static constexpr size_t WS_CNT      = WS_HGLB + 262144;     // 8 grp * 512 t * int

__device__ __forceinline__ float sigmf(float x) { return 1.0f / (1.0f + __expf(-x)); }

// 256 blocks (group = bid&7, slice = bid>>3), 512 threads = 8 waves.
// Weights live in VGPRs for the whole kernel. Per step: k-split FMA over 8 waves,
// LDS tree-reduce, 8-h-col update, cross-block h exchange via global + flags.
__global__ __launch_bounds__(512) void lstm2_kernel(
    const float* __restrict__ z_t, const float* __restrict__ a_t,
    const float* __restrict__ Wx,  const float* __restrict__ Wh,
    const float* __restrict__ bias,
    float* __restrict__ h_glb, int* __restrict__ cnt,
    __hip_bfloat16* __restrict__ outs,
    float* __restrict__ out_c, float* __restrict__ out_h)
{
    const int g    = blockIdx.x & 7;
    const int s    = blockIdx.x >> 3;
    const int tid  = threadIdx.x;
    const int w    = tid >> 6;        // wave id: owns k in [w*32, w*32+32)
    const int lane = tid & 63;
    const int c    = lane & 31;       // slice col: gate = c>>3, j = c&7
    const int bh   = lane >> 5;       // batch half: b in [bh*8, bh*8+8)
    const int gate = c >> 3, jj = c & 7;
    const int gcol = gate * 256 + s * 8 + jj;   // column in [0,1024)

    __shared__ __align__(16) float h_lds[GB][264];   // 256 + pad, 16B-aligned rows
    __shared__ __align__(16) float x_lds[GB][36];
    __shared__ __align__(16) float part[8][GB][SC];
    __shared__ __align__(16) float g_red[GB][SC];

    // zero h(−1) and the x pad slot (LDS is undefined; NaN*0 would poison)
    for (int i = tid; i < GB * 264; i += 512) ((float*)h_lds)[i] = 0.0f;
    if (tid < GB) x_lds[tid][35] = 0.0f;

    // ---- persistent weights in VGPRs (loaded once) ----
    float Wreg[32];
    #pragma unroll
    for (int i = 0; i < 32; ++i) Wreg[i] = Wh[(size_t)(w * 32 + i) * G_DIM + gcol];
    float Wxreg[4], Wxreg2[4];
    #pragma unroll
    for (int i = 0; i < 4; ++i) Wxreg[i] = Wx[(size_t)(w * 4 + i) * G_DIM + gcol];
    #pragma unroll
    for (int i = 0; i < 4; ++i)
        Wxreg2[i] = (w == 0 && (32 + i) < IN_D) ? Wx[(size_t)(32 + i) * G_DIM + gcol] : 0.0f;
    const float bv = (w == 0) ? bias[gcol] : 0.0f;   // bias counted once in the reduce

    float c_reg = 0.0f;               // cell state, owned by threads tid<128
    const int ub = tid >> 3;          // update-phase batch
    const int uj = tid & 7;           // update-phase h-col within slice

    float* hg0 = h_glb + ((size_t)g * 2    ) * GB * H_DIM;
    float* hg1 = h_glb + ((size_t)g * 2 + 1) * GB * H_DIM;
    int*   cg  = cnt + g * T_LEN;

    __syncthreads();

    for (int t = 0; t < T_LEN; ++t) {
        // stage x(t) = concat(z,a) for the 16 batches
        for (int idx = tid; idx < GB * IN_D; idx += 512) {
            int b = idx / IN_D, kk = idx - b * IN_D;
            float v = (kk < 32) ? z_t[((size_t)(g * GB + b) * T_LEN + t) * 32 + kk]
                                : a_t[((size_t)(g * GB + b) * T_LEN + t) * 3 + (kk - 32)];
            x_lds[b][kk] = v;
        }
        if (t > 0) {
            if (tid == 0) {  // wait for all 32 slices of this group to publish h(t-1)
                while (__hip_atomic_load(&cg[t - 1], __ATOMIC_ACQUIRE,
                                         __HIP_MEMORY_SCOPE_AGENT) < NSLICE) {}
            }
            __syncthreads();
            const float4* s4 = (const float4*)(((t - 1) & 1) ? hg1 : hg0);
            float4 v0 = s4[tid * 2], v1 = s4[tid * 2 + 1];
            int b = tid >> 5, k8 = (tid & 31) * 8;
            *(float4*)&h_lds[b][k8]     = v0;
            *(float4*)&h_lds[b][k8 + 4] = v1;
        }
        __syncthreads();

        // ---- FMA phase: partial gates for 8 batches x 1 col x 32 k ----
        #pragma unroll
        for (int j = 0; j < 8; ++j) {
            const int b = bh * 8 + j;
            float acc = bv;
            const float4 xv = *(const float4*)&x_lds[b][w * 4];
            acc = fmaf(xv.x, Wxreg[0], acc);
            acc = fmaf(xv.y, Wxreg[1], acc);
            acc = fmaf(xv.z, Wxreg[2], acc);
            acc = fmaf(xv.w, Wxreg[3], acc);
            if (w == 0) {  // wave-uniform branch: tail xk 32..34 (+zero pad)
                const float4 xv2 = *(const float4*)&x_lds[b][32];
                acc = fmaf(xv2.x, Wxreg2[0], acc);
                acc = fmaf(xv2.y, Wxreg2[1], acc);
                acc = fmaf(xv2.z, Wxreg2[2], acc);
                acc = fmaf(xv2.w, Wxreg2[3], acc);
            }
            const float4* hrow = (const float4*)&h_lds[b][w * 32];
            #pragma unroll
            for (int i4 = 0; i4 < 8; ++i4) {
                float4 hv = hrow[i4];
                acc = fmaf(hv.x, Wreg[i4 * 4 + 0], acc);
                acc = fmaf(hv.y, Wreg[i4 * 4 + 1], acc);
                acc = fmaf(hv.z, Wreg[i4 * 4 + 2], acc);
                acc = fmaf(hv.w, Wreg[i4 * 4 + 3], acc);
            }
            part[w][b][c] = acc;
        }
        __syncthreads();

        // ---- cross-wave k-reduction: one thread per (b, col) ----
        {
            int b = tid >> 5, cc = tid & 31;
            float sum = 0.0f;
            #pragma unroll
            for (int ww = 0; ww < 8; ++ww) sum += part[ww][b][cc];
            g_red[b][cc] = sum;
        }
        __syncthreads();

        // ---- gate nonlinearity + c/h update (16 b x 8 h-cols) ----
        if (tid < 128) {
            float gi = g_red[ub][uj];
            float gf = g_red[ub][8 + uj];
            float gg = g_red[ub][16 + uj];
            float go = g_red[ub][24 + uj];
            float iv = sigmf(gi), fv = sigmf(gf), ov = sigmf(go);
            float gv = tanhf(gg);
            c_reg = fmaf(fv, c_reg, iv * gv);
            float hv = ov * tanhf(c_reg);
            float* dst = (t & 1) ? hg1 : hg0;
            dst[ub * H_DIM + s * 8 + uj] = hv;
            outs[((size_t)(g * GB + ub) * T_LEN + t) * H_DIM + s * 8 + uj] = __float2bfloat16(hv);
            if (t == T_LEN - 1) {
                out_c[(g * GB + ub) * H_DIM + s * 8 + uj] = c_reg;
                out_h[(g * GB + ub) * H_DIM + s * 8 + uj] = hv;
            }
        }
        __syncthreads();   // drains each wave's vmcnt before the release below
        if (tid == 0) {
            __threadfence();
            __hip_atomic_fetch_add(&cg[t], 1, __ATOMIC_RELEASE, __HIP_MEMORY_SCOPE_AGENT);
        }
    }
}

// mdn = outputs(bf16) @ Wd + bd, fused log_softmax(log_pi) and exp(log_sigma)+1e-6.
__global__ __launch_bounds__(256, 1) void mdn_kernel(
    const unsigned short* __restrict__ outputs, const float* __restrict__ Wd,
    const float* __restrict__ bd, float* __restrict__ out)
{
    __shared__ __align__(16) float hT[H_DIM * 16];   // hT[k*16 + r]
    __shared__ float lp[16][K_MIX];

    const int tid = threadIdx.x;
    const long row0 = (long)blockIdx.x * 16;

    // load 16 rows of h (bf16, coalesced), convert, store transposed
    for (int idx = tid; idx < H_DIM * 16; idx += 256) {
        int r = idx >> 8;
        int k = idx & (H_DIM - 1);
        unsigned int u = outputs[(row0 + r) * H_DIM + k];
        hT[k * 16 + r] = __uint_as_float(u << 16);
    }
    __syncthreads();

    const int  cA = tid;
    const int  cB = tid + 256;
    const bool vB = (cB < MDN_D);
    const float bA = bd[cA];
    const float bB = vB ? bd[cB] : 0.0f;
    float accA[16], accB[16];
    #pragma unroll
    for (int r = 0; r < 16; ++r) { accA[r] = bA; accB[r] = bB; }

    for (int k = 0; k < H_DIM; ++k) {
        float wA = Wd[(size_t)k * MDN_D + cA];
        float wB = vB ? Wd[(size_t)k * MDN_D + cB] : 0.0f;
        const float4* hp = (const float4*)(hT + k * 16);
        float4 h0 = hp[0], h1 = hp[1], h2 = hp[2], h3 = hp[3];
        float hr[16] = { h0.x,h0.y,h0.z,h0.w, h1.x,h1.y,h1.z,h1.w,
                         h2.x,h2.y,h2.z,h2.w, h3.x,h3.y,h3.z,h3.w };
        #pragma unroll
        for (int r = 0; r < 16; ++r) {
            accA[r] = fmaf(hr[r], wA, accA[r]);
            accB[r] = fmaf(hr[r], wB, accB[r]);
        }
    }

    float* out_mu = out + OFF_MU;
    float* out_sg = out + OFF_SIGMA;
    #pragma unroll
    for (int r = 0; r < 16; ++r) {
        long row = row0 + r;
        float v = accA[r];
        if (cA < K_MIX)            lp[r][cA] = v;
        else if (cA < K_MIX + 160) out_mu[row * 160 + (cA - K_MIX)] = v;
        else                       out_sg[row * 160 + (cA - 165)]   = __expf(v) + 1e-6f;
        if (vB)                    out_sg[row * 160 + (cB - 165)]   = __expf(accB[r]) + 1e-6f;
    }
    __syncthreads();

    if (tid < 16) {
        int r = tid;
        long row = row0 + r;
        float v0 = lp[r][0], v1 = lp[r][1], v2 = lp[r][2], v3 = lp[r][3], v4 = lp[r][4];
        float m = fmaxf(fmaxf(fmaxf(v0, v1), fmaxf(v2, v3)), v4);
        float sum = __expf(v0-m) + __expf(v1-m) + __expf(v2-m) + __expf(v3-m) + __expf(v4-m);
        float ls = m + __logf(sum);
        out[row*5 + 0] = v0 - ls;
        out[row*5 + 1] = v1 - ls;
        out[row*5 + 2] = v2 - ls;
        out[row*5 + 3] = v3 - ls;
        out[row*5 + 4] = v4 - ls;
    }
}

extern "C" void kernel_launch(void* const* d_in, const int* in_sizes, int n_in,
                              void* d_out, int out_size, void* d_ws, size_t ws_size,
                              hipStream_t stream)
{
    const float* z_t = (const float*)d_in[0];
    const float* a_t = (const float*)d_in[1];
    const float* Wx  = (const float*)d_in[2];
    const float* Wh  = (const float*)d_in[3];
    const float* b   = (const float*)d_in[4];
    const float* Wd  = (const float*)d_in[5];
    const float* bd  = (const float*)d_in[6];
    float* out = (float*)d_out;

    char* ws = (char*)d_ws;
    __hip_bfloat16* outs = (__hip_bfloat16*)(ws + WS_OUT_BF16);
    float* h_glb         = (float*)(ws + WS_HGLB);
    int*   cnt           = (int*)(ws + WS_CNT);

    hipMemsetAsync(cnt, 0, NGROUP * T_LEN * sizeof(int), stream);
    lstm2_kernel<<<NGROUP * NSLICE, 512, 0, stream>>>(z_t, a_t, Wx, Wh, b,
                                                      h_glb, cnt, outs,
                                                      out + OFF_C, out + OFF_H);
    mdn_kernel<<<(B_SZ * T_LEN) / 16, 256, 0, stream>>>((const unsigned short*)outs,
                                                        Wd, bd, out);
}

// Round 3
// 2193.614 us; speedup vs baseline: 3.5887x; 3.5887x over previous
//
#include <hip/hip_runtime.h>
#include <hip/hip_bf16.h>
#include <math.h>

// MDN-RNN: B=128, T=512, Z=32, A=3, H=256, K=5, IN=35, 4H=1024, MDN=325
#define T_LEN 512
#define B_SZ  128
#define H_DIM 256
#define G_DIM 1024
#define IN_D  35
#define MDN_D 325
#define K_MIX 5

#define NSLICE 4     // blocks per group: each owns 64 h-cols x 4 gates = 256 gate cols
#define BG     4     // batches per group
#define NGRP   32    // 128 batches / 4

// d_out layout: log_pi[B,T,5] | mu[B,T,5,32] | sigma[B,T,5,32] | c[B,256] | h[B,256]
static constexpr long OFF_MU    = 327680L;
static constexpr long OFF_SIGMA = 10813440L;
static constexpr long OFF_C     = 21299200L;
static constexpr long OFF_H     = 21331968L;

// ws layout (~33.82 MB; ws >= 64 MB proven in round 1)
static constexpr size_t WS_OUT = 0;          // bf16 outputs: B*T*H*2 = 33,554,432 B
static constexpr size_t WS_HG  = 33554432;   // 32 grp * 2 buf * 4 b * 256 f32 = 256 KB
static constexpr size_t WS_FLG = 33816576;   // 32 grp * 16 int = 2 KB

__device__ __forceinline__ float sigmf(float x) { return 1.0f / (1.0f + __expf(-x)); }

// 128 blocks, 512 threads. Weights VGPR-resident for the whole kernel.
// Thread (cg = tid>>2, kq = tid&3): cols {2cg, 2cg+1} of this block's 256-col slice,
// k-range [kq*64, kq*64+64). Cross-block h exchange: sc0/sc1 (cache-bypass) loads/
// stores + per-slice relaxed flags. No fences, no RMW -> no L2 invalidation.
__global__ __launch_bounds__(512) void lstm3_kernel(
    const float* __restrict__ z_t, const float* __restrict__ a_t,
    const float* __restrict__ Wx,  const float* __restrict__ Wh,
    const float* __restrict__ bias,
    float* __restrict__ h_glb, int* __restrict__ flags,
    __hip_bfloat16* __restrict__ outs,
    float* __restrict__ out_c, float* __restrict__ out_h)
{
    const int bid = blockIdx.x;
    // 4 slices of a group land on one XCD under round-robin (perf heuristic only)
    const int gr  = (bid & 7) * 4 + ((bid >> 3) & 3);
    const int s   = bid >> 5;
    const int tid = threadIdx.x;
    const int cg  = tid >> 2;
    const int kq  = tid & 3;
    const int lc0 = cg * 2;                       // even local col in [0,256)
    const int gate = lc0 >> 6;
    const int j0   = lc0 & 63;
    const int gcol0 = gate * 256 + s * 64 + j0;   // global gate col of lc0

    __shared__ __align__(16) float h_lds[BG][4][68];   // k-sections padded: banks 0/4/8/12
    __shared__ __align__(16) float x_lds[BG][36];
    __shared__ __align__(16) float g_red[BG][256];

    for (int i = tid; i < BG * 4 * 68; i += 512) ((float*)h_lds)[i] = 0.0f;  // h(-1)=0
    if (tid < BG) x_lds[tid][35] = 0.0f;                                     // x pad

    // ---- persistent weights in VGPRs (loaded once; ~146 regs) ----
    float W0[64], W1[64];
    #pragma unroll
    for (int i = 0; i < 64; ++i) {
        const size_t r = (size_t)(kq * 64 + i) * G_DIM;
        W0[i] = Wh[r + gcol0];
        W1[i] = Wh[r + gcol0 + 1];
    }
    float X0[9], X1[9];
    #pragma unroll
    for (int i = 0; i < 9; ++i) {
        int xk = kq * 9 + i;
        bool ok = (xk < IN_D);
        X0[i] = ok ? Wx[(size_t)xk * G_DIM + gcol0]     : 0.0f;
        X1[i] = ok ? Wx[(size_t)xk * G_DIM + gcol0 + 1] : 0.0f;
    }

    // combine-thread state (tid<256): (batch cb, h-col cj) of this slice
    const int cb = tid >> 6;
    const int cj = tid & 63;
    float bc[4];
    #pragma unroll
    for (int g4 = 0; g4 < 4; ++g4) bc[g4] = bias[g4 * 256 + s * 64 + cj];
    float c_reg = 0.0f;

    const int batch0 = gr * BG;
    float* hg = h_glb + (size_t)gr * 2048;        // [2][BG][256]
    int*   fl = flags + gr * 16;

    __syncthreads();

    for (int t = 0; t < T_LEN; ++t) {
        // ---- stage x(t) (independent of h; overlaps the wait) ----
        if (tid < BG * 32) {
            int b = tid >> 5, k = tid & 31;
            x_lds[b][k] = z_t[((size_t)(batch0 + b) * T_LEN + t) * 32 + k];
        } else if (tid >= 128 && tid < 128 + BG * 3) {
            int q = tid - 128, b = q / 3, k = q - 3 * b;
            x_lds[b][32 + k] = a_t[((size_t)(batch0 + b) * T_LEN + t) * 3 + k];
        }

        if (t > 0) {
            if (tid == 0) {   // poll 4 per-slice flags (relaxed, no fence, no RMW)
                while (true) {
                    int f0 = __hip_atomic_load(fl + 0, __ATOMIC_RELAXED, __HIP_MEMORY_SCOPE_AGENT);
                    int f1 = __hip_atomic_load(fl + 1, __ATOMIC_RELAXED, __HIP_MEMORY_SCOPE_AGENT);
                    int f2 = __hip_atomic_load(fl + 2, __ATOMIC_RELAXED, __HIP_MEMORY_SCOPE_AGENT);
                    int f3 = __hip_atomic_load(fl + 3, __ATOMIC_RELAXED, __HIP_MEMORY_SCOPE_AGENT);
                    if (f0 >= t && f1 >= t && f2 >= t && f3 >= t) break;
                }
            }
            __syncthreads();
            if (tid < 256) {   // fetch h(t-1): 4 KB via cache-bypass 16B loads
                const float4* src = (const float4*)(hg + ((t & 1) ^ 1) * 1024) + tid;
                float4 hv;
                asm volatile("global_load_dwordx4 %0, %1, off sc0 sc1\n\ts_waitcnt vmcnt(0)"
                             : "=v"(hv) : "v"(src) : "memory");
                int b = tid >> 6, k4 = (tid & 63) * 4;
                *(float4*)&h_lds[b][k4 >> 6][k4 & 63] = hv;
            }
        }
        __syncthreads();

        // ---- FMA phase: 4 batches x 2 cols x 64 k per thread ----
        float acc[BG][2];
        #pragma unroll
        for (int b = 0; b < BG; ++b) { acc[b][0] = 0.0f; acc[b][1] = 0.0f; }
        #pragma unroll
        for (int b = 0; b < BG; ++b) {
            const float4* hp = (const float4*)h_lds[b][kq];
            #pragma unroll
            for (int i4 = 0; i4 < 16; ++i4) {
                float4 hv = hp[i4];
                acc[b][0] = fmaf(hv.x, W0[i4*4+0], acc[b][0]);
                acc[b][0] = fmaf(hv.y, W0[i4*4+1], acc[b][0]);
                acc[b][0] = fmaf(hv.z, W0[i4*4+2], acc[b][0]);
                acc[b][0] = fmaf(hv.w, W0[i4*4+3], acc[b][0]);
                acc[b][1] = fmaf(hv.x, W1[i4*4+0], acc[b][1]);
                acc[b][1] = fmaf(hv.y, W1[i4*4+1], acc[b][1]);
                acc[b][1] = fmaf(hv.z, W1[i4*4+2], acc[b][1]);
                acc[b][1] = fmaf(hv.w, W1[i4*4+3], acc[b][1]);
            }
            const float* xp = &x_lds[b][kq * 9];
            #pragma unroll
            for (int i = 0; i < 9; ++i) {
                float xv = xp[i];
                acc[b][0] = fmaf(xv, X0[i], acc[b][0]);
                acc[b][1] = fmaf(xv, X1[i], acc[b][1]);
            }
        }
        // ---- k-reduce across the 4 kq lanes (butterfly within lane-quad) ----
        #pragma unroll
        for (int b = 0; b < BG; ++b) {
            #pragma unroll
            for (int c2 = 0; c2 < 2; ++c2) {
                float v = acc[b][c2];
                v += __shfl_xor(v, 1, 64);
                v += __shfl_xor(v, 2, 64);
                acc[b][c2] = v;
            }
        }
        if (kq == 0) {
            #pragma unroll
            for (int b = 0; b < BG; ++b) {
                g_red[b][lc0]     = acc[b][0];
                g_red[b][lc0 + 1] = acc[b][1];
            }
        }
        __syncthreads();

        // ---- gate nonlinearity + c/h update; publish h slice ----
        if (tid < 256) {
            float gi = g_red[cb][      cj] + bc[0];
            float gf = g_red[cb][ 64 + cj] + bc[1];
            float gg = g_red[cb][128 + cj] + bc[2];
            float go = g_red[cb][192 + cj] + bc[3];
            float iv = sigmf(gi), fv = sigmf(gf), ov = sigmf(go);
            float gv = tanhf(gg);
            c_reg = fmaf(fv, c_reg, iv * gv);
            float hv = ov * tanhf(c_reg);
            float* dst = hg + (t & 1) * 1024 + cb * 256 + s * 64 + cj;
            asm volatile("global_store_dword %0, %1, off sc0 sc1"
                         :: "v"(dst), "v"(hv) : "memory");
            outs[((size_t)(batch0 + cb) * T_LEN + t) * H_DIM + s * 64 + cj] =
                __float2bfloat16(hv);
            if (t == T_LEN - 1) {
                out_c[(batch0 + cb) * H_DIM + s * 64 + cj] = c_reg;
                out_h[(batch0 + cb) * H_DIM + s * 64 + cj] = hv;
            }
        }
        asm volatile("s_waitcnt vmcnt(0)" ::: "memory");  // h stores at coherence point
        __syncthreads();
        if (tid == 0)
            __hip_atomic_store(fl + s, t + 1, __ATOMIC_RELAXED, __HIP_MEMORY_SCOPE_AGENT);
    }
}

// mdn = outputs(bf16) @ Wd + bd, fused log_softmax(log_pi) and exp(log_sigma)+1e-6.
__global__ __launch_bounds__(256, 1) void mdn_kernel(
    const unsigned short* __restrict__ outputs, const float* __restrict__ Wd,
    const float* __restrict__ bd, float* __restrict__ out)
{
    __shared__ __align__(16) float hT[H_DIM * 16];   // hT[k*16 + r]
    __shared__ float lp[16][K_MIX];

    const int tid = threadIdx.x;
    const long row0 = (long)blockIdx.x * 16;

    for (int idx = tid; idx < H_DIM * 16; idx += 256) {
        int r = idx >> 8;
        int k = idx & (H_DIM - 1);
        unsigned int u = outputs[(row0 + r) * H_DIM + k];
        hT[k * 16 + r] = __uint_as_float(u << 16);
    }
    __syncthreads();

    const int  cA = tid;
    const int  cB = tid + 256;
    const bool vB = (cB < MDN_D);
    const float bA = bd[cA];
    const float bB = vB ? bd[cB] : 0.0f;
    float accA[16], accB[16];
    #pragma unroll
    for (int r = 0; r < 16; ++r) { accA[r] = bA; accB[r] = bB; }

    for (int k = 0; k < H_DIM; ++k) {
        float wA = Wd[(size_t)k * MDN_D + cA];
        float wB = vB ? Wd[(size_t)k * MDN_D + cB] : 0.0f;
        const float4* hp = (const float4*)(hT + k * 16);
        float4 h0 = hp[0], h1 = hp[1], h2 = hp[2], h3 = hp[3];
        float hr[16] = { h0.x,h0.y,h0.z,h0.w, h1.x,h1.y,h1.z,h1.w,
                         h2.x,h2.y,h2.z,h2.w, h3.x,h3.y,h3.z,h3.w };
        #pragma unroll
        for (int r = 0; r < 16; ++r) {
            accA[r] = fmaf(hr[r], wA, accA[r]);
            accB[r] = fmaf(hr[r], wB, accB[r]);
        }
    }

    float* out_mu = out + OFF_MU;
    float* out_sg = out + OFF_SIGMA;
    #pragma unroll
    for (int r = 0; r < 16; ++r) {
        long row = row0 + r;
        float v = accA[r];
        if (cA < K_MIX)            lp[r][cA] = v;
        else if (cA < K_MIX + 160) out_mu[row * 160 + (cA - K_MIX)] = v;
        else                       out_sg[row * 160 + (cA - 165)]   = __expf(v) + 1e-6f;
        if (vB)                    out_sg[row * 160 + (cB - 165)]   = __expf(accB[r]) + 1e-6f;
    }
    __syncthreads();

    if (tid < 16) {
        int r = tid;
        long row = row0 + r;
        float v0 = lp[r][0], v1 = lp[r][1], v2 = lp[r][2], v3 = lp[r][3], v4 = lp[r][4];
        float m = fmaxf(fmaxf(fmaxf(v0, v1), fmaxf(v2, v3)), v4);
        float sum = __expf(v0-m) + __expf(v1-m) + __expf(v2-m) + __expf(v3-m) + __expf(v4-m);
        float ls = m + __logf(sum);
        out[row*5 + 0] = v0 - ls;
        out[row*5 + 1] = v1 - ls;
        out[row*5 + 2] = v2 - ls;
        out[row*5 + 3] = v3 - ls;
        out[row*5 + 4] = v4 - ls;
    }
}

extern "C" void kernel_launch(void* const* d_in, const int* in_sizes, int n_in,
                              void* d_out, int out_size, void* d_ws, size_t ws_size,
                              hipStream_t stream)
{
    const float* z_t = (const float*)d_in[0];
    const float* a_t = (const float*)d_in[1];
    const float* Wx  = (const float*)d_in[2];
    const float* Wh  = (const float*)d_in[3];
    const float* b   = (const float*)d_in[4];
    const float* Wd  = (const float*)d_in[5];
    const float* bd  = (const float*)d_in[6];
    float* out = (float*)d_out;

    char* ws = (char*)d_ws;
    __hip_bfloat16* outs = (__hip_bfloat16*)(ws + WS_OUT);
    float* h_glb         = (float*)(ws + WS_HG);
    int*   flags         = (int*)(ws + WS_FLG);

    hipMemsetAsync(flags, 0, NGRP * 16 * sizeof(int), stream);
    lstm3_kernel<<<NGRP * NSLICE, 512, 0, stream>>>(z_t, a_t, Wx, Wh, b,
                                                    h_glb, flags, outs,
                                                    out + OFF_C, out + OFF_H);
    mdn_kernel<<<(B_SZ * T_LEN) / 16, 256, 0, stream>>>((const unsigned short*)outs,
                                                        Wd, bd, out);
}

// Round 4
// 1258.855 us; speedup vs baseline: 6.2535x; 1.7425x over previous
//
#include <hip/hip_runtime.h>
#include <hip/hip_bf16.h>
#include <math.h>

// MDN-RNN: B=128, T=512, Z=32, A=3, H=256, K=5, IN=35, 4H=1024, MDN=325
#define T_LEN 512
#define B_SZ  128
#define H_DIM 256
#define G_DIM 1024
#define IN_D  35
#define MDN_D 325
#define K_MIX 5

#define NSLICE 4     // gate-dim slices per group (each owns 64 h-cols x 4 gates)
#define BG     2     // batches per group
#define NGRP   64    // 128 / BG   -> 256 blocks total = 1/CU (co-residency proven R2)

// d_out layout: log_pi[B,T,5] | mu[B,T,5,32] | sigma[B,T,5,32] | c[B,256] | h[B,256]
static constexpr long OFF_MU    = 327680L;
static constexpr long OFF_SIGMA = 10813440L;
static constexpr long OFF_C     = 21299200L;
static constexpr long OFF_H     = 21331968L;

// ws layout (~34 MB; ws >= 64 MiB proven in round 1)
static constexpr size_t WS_OUT = 0;          // bf16 outs: B*T*H*2 = 33,554,432 B
static constexpr size_t WS_HG  = 33554432;   // 64 grp * 2 par * 2 b * 256 f32 = 512 KB

__device__ __forceinline__ float fast_sigmoid(float x) { return 1.0f / (1.0f + __expf(-x)); }
__device__ __forceinline__ float fast_tanh(float x) {
    // 1 - 2/(e^{2x}+1); saturates to +-1 correctly at +-inf
    return 1.0f - 2.0f / (__expf(2.0f * x) + 1.0f);
}

// 256 blocks (group = bid&63, slice = bid>>6), 512 threads.
// Weights VGPR-resident. h exchange: SELF-VALIDATING dwords — h in (-1,1), low 2
// mantissa bits carry t&3. Writer stores tagged dword (sc0 sc1, no drain, no flag);
// each reader polls its one dword until tag==(t-1)&3 — the detecting load IS the
// data load. Double-buffered by t&1; skew<=1 makes mod-4 tags unambiguous; 0xAA
// poison / stale-run leftovers never alias the wanted tag, so no memset needed.
__global__ __launch_bounds__(512) void lstm4_kernel(
    const float* __restrict__ z_t, const float* __restrict__ a_t,
    const float* __restrict__ Wx,  const float* __restrict__ Wh,
    const float* __restrict__ bias,
    float* __restrict__ h_glb,
    __hip_bfloat16* __restrict__ outs,
    float* __restrict__ out_c, float* __restrict__ out_h)
{
    const int bid = blockIdx.x;
    const int gr  = bid & 63;
    const int s   = bid >> 6;
    const int tid = threadIdx.x;
    const int cg  = tid >> 2;              // 0..127 -> cols {2cg, 2cg+1} of slice
    const int kq  = tid & 3;               // k-range [kq*64, kq*64+64)
    const int lc0 = cg * 2;
    const int gate = lc0 >> 6;
    const int j0   = lc0 & 63;
    const int gcol0 = gate * 256 + s * 64 + j0;

    __shared__ __align__(16) float h_lds[BG][4][68];   // kq sections padded (+4)
    __shared__ __align__(16) float x_lds[BG][36];
    __shared__ __align__(16) float g_red[BG][256];

    for (int i = tid; i < BG * 4 * 68; i += 512) ((float*)h_lds)[i] = 0.0f;  // h(-1)=0
    if (tid < BG) x_lds[tid][35] = 0.0f;                                     // x pad

    // ---- persistent weights in VGPRs (loaded once, ~146 regs) ----
    float W0[64], W1[64];
    #pragma unroll
    for (int i = 0; i < 64; ++i) {
        const size_t r = (size_t)(kq * 64 + i) * G_DIM;
        W0[i] = Wh[r + gcol0];
        W1[i] = Wh[r + gcol0 + 1];
    }
    float X0[9], X1[9];
    #pragma unroll
    for (int i = 0; i < 9; ++i) {
        int xk = kq * 9 + i;
        bool ok = (xk < IN_D);
        X0[i] = ok ? Wx[(size_t)xk * G_DIM + gcol0]     : 0.0f;
        X1[i] = ok ? Wx[(size_t)xk * G_DIM + gcol0 + 1] : 0.0f;
    }

    // writer role (tid<128): batch cb, h-col cj of this slice
    const int cb = tid >> 6;
    const int cj = tid & 63;
    const float bc0 = bias[0 * 256 + s * 64 + cj];
    const float bc1 = bias[1 * 256 + s * 64 + cj];
    const float bc2 = bias[2 * 256 + s * 64 + cj];
    const float bc3 = bias[3 * 256 + s * 64 + cj];
    float c_reg = 0.0f;

    const int batch0 = gr * BG;
    float* hg = h_glb + (size_t)gr * (2 * BG * H_DIM);   // [2][BG][256]

    __syncthreads();

    for (int t = 0; t < T_LEN; ++t) {
        // ---- stage x(t): issue before polling so the HBM latency overlaps ----
        if (tid >= 128 && tid < 192) {
            int q = tid - 128, b = q >> 5, k = q & 31;
            x_lds[b][k] = z_t[((size_t)(batch0 + b) * T_LEN + t) * 32 + k];
        } else if (tid >= 192 && tid < 192 + BG * 3) {
            int q = tid - 192, b = (q >= 3), k = q - 3 * b;
            x_lds[b][32 + k] = a_t[((size_t)(batch0 + b) * T_LEN + t) * 3 + k];
        }

        // ---- fetch h(t-1): one self-validating dword per thread ----
        if (t > 0) {
            const unsigned want = (unsigned)((t - 1) & 3);
            const float* ap = hg + ((t - 1) & 1) * (BG * H_DIM) + tid;  // tid = b*256+k
            unsigned u;
            do {
                asm volatile("global_load_dword %0, %1, off sc0 sc1\n\t"
                             "s_waitcnt vmcnt(0)"
                             : "=v"(u) : "v"(ap) : "memory");
            } while ((u & 3u) != want);
            int b = tid >> 8, k = tid & 255;
            h_lds[b][k >> 6][k & 63] = __uint_as_float(u);
        }
        __syncthreads();

        // ---- FMA: 2 batches x 2 cols x 73 k per thread ----
        float a00 = 0.0f, a01 = 0.0f, a10 = 0.0f, a11 = 0.0f;
        {
            const float4* hp0 = (const float4*)h_lds[0][kq];
            const float4* hp1 = (const float4*)h_lds[1][kq];
            #pragma unroll
            for (int i4 = 0; i4 < 16; ++i4) {
                float4 hv0 = hp0[i4];
                float4 hv1 = hp1[i4];
                a00 = fmaf(hv0.x, W0[4*i4+0], a00); a01 = fmaf(hv0.x, W1[4*i4+0], a01);
                a10 = fmaf(hv1.x, W0[4*i4+0], a10); a11 = fmaf(hv1.x, W1[4*i4+0], a11);
                a00 = fmaf(hv0.y, W0[4*i4+1], a00); a01 = fmaf(hv0.y, W1[4*i4+1], a01);
                a10 = fmaf(hv1.y, W0[4*i4+1], a10); a11 = fmaf(hv1.y, W1[4*i4+1], a11);
                a00 = fmaf(hv0.z, W0[4*i4+2], a00); a01 = fmaf(hv0.z, W1[4*i4+2], a01);
                a10 = fmaf(hv1.z, W0[4*i4+2], a10); a11 = fmaf(hv1.z, W1[4*i4+2], a11);
                a00 = fmaf(hv0.w, W0[4*i4+3], a00); a01 = fmaf(hv0.w, W1[4*i4+3], a01);
                a10 = fmaf(hv1.w, W0[4*i4+3], a10); a11 = fmaf(hv1.w, W1[4*i4+3], a11);
            }
            const float* xp0 = &x_lds[0][kq * 9];
            const float* xp1 = &x_lds[1][kq * 9];
            #pragma unroll
            for (int i = 0; i < 9; ++i) {
                float xv0 = xp0[i], xv1 = xp1[i];
                a00 = fmaf(xv0, X0[i], a00); a01 = fmaf(xv0, X1[i], a01);
                a10 = fmaf(xv1, X0[i], a10); a11 = fmaf(xv1, X1[i], a11);
            }
        }
        // ---- k-reduce across the 4 kq lanes of each quad ----
        a00 += __shfl_xor(a00, 1, 64); a00 += __shfl_xor(a00, 2, 64);
        a01 += __shfl_xor(a01, 1, 64); a01 += __shfl_xor(a01, 2, 64);
        a10 += __shfl_xor(a10, 1, 64); a10 += __shfl_xor(a10, 2, 64);
        a11 += __shfl_xor(a11, 1, 64); a11 += __shfl_xor(a11, 2, 64);
        if (kq == 0) {
            g_red[0][lc0] = a00; g_red[0][lc0 + 1] = a01;
            g_red[1][lc0] = a10; g_red[1][lc0 + 1] = a11;
        }
        __syncthreads();

        // ---- nonlinearity + c/h update + tagged publish (no barrier after) ----
        if (tid < 128) {
            float gi = g_red[cb][      cj] + bc0;
            float gf = g_red[cb][ 64 + cj] + bc1;
            float gg = g_red[cb][128 + cj] + bc2;
            float go = g_red[cb][192 + cj] + bc3;
            float iv = fast_sigmoid(gi), fv = fast_sigmoid(gf), ov = fast_sigmoid(go);
            float gv = fast_tanh(gg);
            c_reg = fmaf(fv, c_reg, iv * gv);
            float hv = ov * fast_tanh(c_reg);
            unsigned u = (__float_as_uint(hv) & ~3u) | (unsigned)(t & 3);
            float* dst = hg + (t & 1) * (BG * H_DIM) + cb * H_DIM + s * 64 + cj;
            asm volatile("global_store_dword %0, %1, off sc0 sc1"
                         :: "v"(dst), "v"(u) : "memory");
            outs[((size_t)(batch0 + cb) * T_LEN + t) * H_DIM + s * 64 + cj] =
                __float2bfloat16(hv);
            if (t == T_LEN - 1) {
                out_c[(batch0 + cb) * H_DIM + s * 64 + cj] = c_reg;
                out_h[(batch0 + cb) * H_DIM + s * 64 + cj] = hv;
            }
        }
        // next iteration's polls gate on these stores (incl. our own) — no sync needed
    }
}

// mdn = outputs(bf16) @ Wd + bd, fused log_softmax(log_pi) and exp(log_sigma)+1e-6.
__global__ __launch_bounds__(256, 1) void mdn_kernel(
    const unsigned short* __restrict__ outputs, const float* __restrict__ Wd,
    const float* __restrict__ bd, float* __restrict__ out)
{
    __shared__ __align__(16) float hT[H_DIM * 16];   // hT[k*16 + r]
    __shared__ float lp[16][K_MIX];

    const int tid = threadIdx.x;
    const long row0 = (long)blockIdx.x * 16;

    for (int idx = tid; idx < H_DIM * 16; idx += 256) {
        int r = idx >> 8;
        int k = idx & (H_DIM - 1);
        unsigned int u = outputs[(row0 + r) * H_DIM + k];
        hT[k * 16 + r] = __uint_as_float(u << 16);
    }
    __syncthreads();

    const int  cA = tid;
    const int  cB = tid + 256;
    const bool vB = (cB < MDN_D);
    const float bA = bd[cA];
    const float bB = vB ? bd[cB] : 0.0f;
    float accA[16], accB[16];
    #pragma unroll
    for (int r = 0; r < 16; ++r) { accA[r] = bA; accB[r] = bB; }

    for (int k = 0; k < H_DIM; ++k) {
        float wA = Wd[(size_t)k * MDN_D + cA];
        float wB = vB ? Wd[(size_t)k * MDN_D + cB] : 0.0f;
        const float4* hp = (const float4*)(hT + k * 16);
        float4 h0 = hp[0], h1 = hp[1], h2 = hp[2], h3 = hp[3];
        float hr[16] = { h0.x,h0.y,h0.z,h0.w, h1.x,h1.y,h1.z,h1.w,
                         h2.x,h2.y,h2.z,h2.w, h3.x,h3.y,h3.z,h3.w };
        #pragma unroll
        for (int r = 0; r < 16; ++r) {
            accA[r] = fmaf(hr[r], wA, accA[r]);
            accB[r] = fmaf(hr[r], wB, accB[r]);
        }
    }

    float* out_mu = out + OFF_MU;
    float* out_sg = out + OFF_SIGMA;
    #pragma unroll
    for (int r = 0; r < 16; ++r) {
        long row = row0 + r;
        float v = accA[r];
        if (cA < K_MIX)            lp[r][cA] = v;
        else if (cA < K_MIX + 160) out_mu[row * 160 + (cA - K_MIX)] = v;
        else                       out_sg[row * 160 + (cA - 165)]   = __expf(v) + 1e-6f;
        if (vB)                    out_sg[row * 160 + (cB - 165)]   = __expf(accB[r]) + 1e-6f;
    }
    __syncthreads();

    if (tid < 16) {
        int r = tid;
        long row = row0 + r;
        float v0 = lp[r][0], v1 = lp[r][1], v2 = lp[r][2], v3 = lp[r][3], v4 = lp[r][4];
        float m = fmaxf(fmaxf(fmaxf(v0, v1), fmaxf(v2, v3)), v4);
        float sum = __expf(v0-m) + __expf(v1-m) + __expf(v2-m) + __expf(v3-m) + __expf(v4-m);
        float ls = m + __logf(sum);
        out[row*5 + 0] = v0 - ls;
        out[row*5 + 1] = v1 - ls;
        out[row*5 + 2] = v2 - ls;
        out[row*5 + 3] = v3 - ls;
        out[row*5 + 4] = v4 - ls;
    }
}

extern "C" void kernel_launch(void* const* d_in, const int* in_sizes, int n_in,
                              void* d_out, int out_size, void* d_ws, size_t ws_size,
                              hipStream_t stream)
{
    const float* z_t = (const float*)d_in[0];
    const float* a_t = (const float*)d_in[1];
    const float* Wx  = (const float*)d_in[2];
    const float* Wh  = (const float*)d_in[3];
    const float* b   = (const float*)d_in[4];
    const float* Wd  = (const float*)d_in[5];
    const float* bd  = (const float*)d_in[6];
    float* out = (float*)d_out;

    char* ws = (char*)d_ws;
    __hip_bfloat16* outs = (__hip_bfloat16*)(ws + WS_OUT);
    float* h_glb         = (float*)(ws + WS_HG);

    lstm4_kernel<<<NGRP * NSLICE, 512, 0, stream>>>(z_t, a_t, Wx, Wh, b,
                                                    h_glb, outs,
                                                    out + OFF_C, out + OFF_H);
    mdn_kernel<<<(B_SZ * T_LEN) / 16, 256, 0, stream>>>((const unsigned short*)outs,
                                                        Wd, bd, out);
}

// Round 5
// 1206.077 us; speedup vs baseline: 6.5272x; 1.0438x over previous
//
#include <hip/hip_runtime.h>
#include <hip/hip_bf16.h>
#include <math.h>

// MDN-RNN: B=128, T=512, Z=32, A=3, H=256, K=5, IN=35, 4H=1024, MDN=325
#define T_LEN 512
#define B_SZ  128
#define H_DIM 256
#define G_DIM 1024
#define IN_D  35
#define MDN_D 325
#define K_MIX 5

#define NSLICE 4     // gate-dim slices per group (each owns 64 h-cols x 4 gates)
#define BG     2     // batches per group
#define NGRP   64    // 128 / BG   -> 256 blocks total = 1/CU

// d_out layout: log_pi[B,T,5] | mu[B,T,5,32] | sigma[B,T,5,32] | c[B,256] | h[B,256]
static constexpr long OFF_MU    = 327680L;
static constexpr long OFF_SIGMA = 10813440L;
static constexpr long OFF_C     = 21299200L;
static constexpr long OFF_H     = 21331968L;

// ws layout (~34 MB; ws >= 64 MiB proven in round 1)
static constexpr size_t WS_OUT = 0;          // bf16 outs: B*T*H*2 = 33,554,432 B
static constexpr size_t WS_HG  = 33554432;   // 64 grp * 2 par * 2 b * 256 f32 = 512 KB

typedef unsigned uint2v __attribute__((ext_vector_type(2)));

__device__ __forceinline__ float fast_sigmoid(float x) { return 1.0f / (1.0f + __expf(-x)); }
__device__ __forceinline__ float fast_tanh(float x) {
    return 1.0f - 2.0f / (__expf(2.0f * x) + 1.0f);
}

// 256 blocks (group=bid&63, slice=bid>>6), 512 threads, weights VGPR-resident
// (launch_bounds(512,1): up to 256 VGPR/wave so weights are NOT parked in AGPRs).
// h exchange: self-validating dwords (h in (-1,1); low 2 mantissa bits = t&3).
// Role split: waves 0-1 = writers (publish, never poll -> store acks off the
// critical path; own slice written straight to LDS), waves 2-4 = pollers
// (192 thr x dwordx2 over the 384 foreign dwords), wave 6 = x stagers
// (stage x(t+1) during phase C -> HBM latency never meets a poll vmcnt(0)).
__global__ __launch_bounds__(512, 1) void lstm5_kernel(
    const float* __restrict__ z_t, const float* __restrict__ a_t,
    const float* __restrict__ Wx,  const float* __restrict__ Wh,
    const float* __restrict__ bias,
    float* __restrict__ h_glb,
    __hip_bfloat16* __restrict__ outs,
    float* __restrict__ out_c, float* __restrict__ out_h)
{
    const int bid = blockIdx.x;
    const int gr  = bid & 63;
    const int s   = bid >> 6;
    const int tid = threadIdx.x;
    const int cg  = tid >> 2;              // cols {2cg, 2cg+1} of this 256-col slice
    const int kq  = tid & 3;               // k-range [kq*64, kq*64+64)
    const int lc0 = cg * 2;
    const int gate = lc0 >> 6;
    const int j0   = lc0 & 63;
    const int gcol0 = gate * 256 + s * 64 + j0;

    __shared__ __align__(16) float h_lds[BG][4][68];   // kq sections padded (+4)
    __shared__ __align__(16) float x_lds[BG][36];
    __shared__ __align__(16) float g_red[BG][256];

    for (int i = tid; i < BG * 4 * 68; i += 512) ((float*)h_lds)[i] = 0.0f;  // h(-1)=0
    if (tid < BG) x_lds[tid][35] = 0.0f;                                     // x pad

    // ---- persistent weights in VGPRs (loaded once) ----
    float W0[64], W1[64];
    #pragma unroll
    for (int i = 0; i < 64; ++i) {
        const size_t r = (size_t)(kq * 64 + i) * G_DIM;
        W0[i] = Wh[r + gcol0];
        W1[i] = Wh[r + gcol0 + 1];
    }
    float X0[9], X1[9];
    #pragma unroll
    for (int i = 0; i < 9; ++i) {
        int xk = kq * 9 + i;
        bool ok = (xk < IN_D);
        X0[i] = ok ? Wx[(size_t)xk * G_DIM + gcol0]     : 0.0f;
        X1[i] = ok ? Wx[(size_t)xk * G_DIM + gcol0 + 1] : 0.0f;
    }

    // writer role (tid<128): batch cb, h-col cj of this slice
    const int cb = tid >> 6;
    const int cj = tid & 63;
    const float bc0 = bias[0 * 256 + s * 64 + cj];
    const float bc1 = bias[1 * 256 + s * 64 + cj];
    const float bc2 = bias[2 * 256 + s * 64 + cj];
    const float bc3 = bias[3 * 256 + s * 64 + cj];
    float c_reg = 0.0f;

    // poller role (tid in [128,320)): q -> foreign dword pair (b, kk)
    const int q  = tid - 128;              // 0..191
    const int pb = (q >= 96) ? 1 : 0;
    const int pp = q - 96 * pb;            // 0..95
    const int pk0 = pp * 2;
    const int pkk = pk0 + ((pk0 >= s * 64) ? 64 : 0);   // skip own slice's 64-chunk

    const int batch0 = gr * BG;
    float* hg = h_glb + (size_t)gr * (2 * BG * H_DIM);   // [2][BG][256]

    // ---- pre-loop: stage x(0) ----
    if (tid >= 384 && tid < 448) {
        int qq = tid - 384, b = qq >> 5, k = qq & 31;
        x_lds[b][k] = z_t[((size_t)(batch0 + b) * T_LEN + 0) * 32 + k];
    } else if (tid >= 448 && tid < 448 + BG * 3) {
        int qq = tid - 448, b = (qq >= 3), k = qq - 3 * b;
        x_lds[b][32 + k] = a_t[((size_t)(batch0 + b) * T_LEN + 0) * 3 + k];
    }
    __syncthreads();

    for (int t = 0; t < T_LEN; ++t) {
        // ---- (A) pollers fetch foreign h(t-1): self-validating dword pairs ----
        if (t > 0 && tid >= 128 && tid < 320) {
            const unsigned want = (unsigned)((t - 1) & 3);
            const float* ap = hg + ((t - 1) & 1) * (BG * H_DIM) + pb * H_DIM + pkk;
            uint2v u;
            do {
                asm volatile("global_load_dwordx2 %0, %1, off sc0 sc1\n\t"
                             "s_waitcnt vmcnt(0)"
                             : "=v"(u) : "v"(ap) : "memory");
            } while ((u.x & 3u) != want || (u.y & 3u) != want);
            float* dst = &h_lds[pb][pkk >> 6][pkk & 63];
            dst[0] = __uint_as_float(u.x);
            dst[1] = __uint_as_float(u.y);
        }
        __syncthreads();   // B1: h_lds + x_lds(t) ready

        // ---- (B) FMA: 2 batches x 2 cols x 73 k per thread ----
        float a00 = 0.0f, a01 = 0.0f, a10 = 0.0f, a11 = 0.0f;
        {
            const float4* hp0 = (const float4*)h_lds[0][kq];
            const float4* hp1 = (const float4*)h_lds[1][kq];
            #pragma unroll
            for (int i4 = 0; i4 < 16; ++i4) {
                float4 hv0 = hp0[i4];
                float4 hv1 = hp1[i4];
                a00 = fmaf(hv0.x, W0[4*i4+0], a00); a01 = fmaf(hv0.x, W1[4*i4+0], a01);
                a10 = fmaf(hv1.x, W0[4*i4+0], a10); a11 = fmaf(hv1.x, W1[4*i4+0], a11);
                a00 = fmaf(hv0.y, W0[4*i4+1], a00); a01 = fmaf(hv0.y, W1[4*i4+1], a01);
                a10 = fmaf(hv1.y, W0[4*i4+1], a10); a11 = fmaf(hv1.y, W1[4*i4+1], a11);
                a00 = fmaf(hv0.z, W0[4*i4+2], a00); a01 = fmaf(hv0.z, W1[4*i4+2], a01);
                a10 = fmaf(hv1.z, W0[4*i4+2], a10); a11 = fmaf(hv1.z, W1[4*i4+2], a11);
                a00 = fmaf(hv0.w, W0[4*i4+3], a00); a01 = fmaf(hv0.w, W1[4*i4+3], a01);
                a10 = fmaf(hv1.w, W0[4*i4+3], a10); a11 = fmaf(hv1.w, W1[4*i4+3], a11);
            }
            const float* xp0 = &x_lds[0][kq * 9];
            const float* xp1 = &x_lds[1][kq * 9];
            #pragma unroll
            for (int i = 0; i < 9; ++i) {
                float xv0 = xp0[i], xv1 = xp1[i];
                a00 = fmaf(xv0, X0[i], a00); a01 = fmaf(xv0, X1[i], a01);
                a10 = fmaf(xv1, X0[i], a10); a11 = fmaf(xv1, X1[i], a11);
            }
        }
        // k-reduce across the 4 kq lanes of each quad
        a00 += __shfl_xor(a00, 1, 64); a00 += __shfl_xor(a00, 2, 64);
        a01 += __shfl_xor(a01, 1, 64); a01 += __shfl_xor(a01, 2, 64);
        a10 += __shfl_xor(a10, 1, 64); a10 += __shfl_xor(a10, 2, 64);
        a11 += __shfl_xor(a11, 1, 64); a11 += __shfl_xor(a11, 2, 64);
        if (kq == 0) {
            g_red[0][lc0] = a00; g_red[0][lc0 + 1] = a01;
            g_red[1][lc0] = a10; g_red[1][lc0 + 1] = a11;
        }
        __syncthreads();   // B2: g_red ready; FMA reads of h_lds/x_lds done

        // ---- (C) writers: nonlin + c/h update + tagged publish + local h_lds ----
        if (tid < 128) {
            float gi = g_red[cb][      cj] + bc0;
            float gf = g_red[cb][ 64 + cj] + bc1;
            float gg = g_red[cb][128 + cj] + bc2;
            float go = g_red[cb][192 + cj] + bc3;
            float iv = fast_sigmoid(gi), fv = fast_sigmoid(gf), ov = fast_sigmoid(go);
            float gv = fast_tanh(gg);
            c_reg = fmaf(fv, c_reg, iv * gv);
            float hv = ov * fast_tanh(c_reg);
            unsigned u = (__float_as_uint(hv) & ~3u) | (unsigned)(t & 3);
            float* dst = hg + (t & 1) * (BG * H_DIM) + cb * H_DIM + s * 64 + cj;
            asm volatile("global_store_dword %0, %1, off sc0 sc1"
                         :: "v"(dst), "v"(u) : "memory");
            h_lds[cb][s][cj] = __uint_as_float(u);   // own slice: no IC round trip
            outs[((size_t)(batch0 + cb) * T_LEN + t) * H_DIM + s * 64 + cj] =
                __float2bfloat16(hv);
            if (t == T_LEN - 1) {
                out_c[(batch0 + cb) * H_DIM + s * 64 + cj] = c_reg;
                out_h[(batch0 + cb) * H_DIM + s * 64 + cj] = hv;
            }
        }
        // ---- (C) stagers: x(t+1) -> x_lds (FMA readers are already past B2) ----
        if (t + 1 < T_LEN) {
            if (tid >= 384 && tid < 448) {
                int qq = tid - 384, b = qq >> 5, k = qq & 31;
                x_lds[b][k] = z_t[((size_t)(batch0 + b) * T_LEN + (t + 1)) * 32 + k];
            } else if (tid >= 448 && tid < 448 + BG * 3) {
                int qq = tid - 448, b = (qq >= 3), k = qq - 3 * b;
                x_lds[b][32 + k] = a_t[((size_t)(batch0 + b) * T_LEN + (t + 1)) * 3 + k];
            }
        }
        // next iteration's B1 orders all LDS writes; pollers gate on foreign stores
    }
}

// mdn = outputs(bf16) @ Wd + bd, fused log_softmax(log_pi) and exp(log_sigma)+1e-6.
__global__ __launch_bounds__(256, 1) void mdn_kernel(
    const unsigned short* __restrict__ outputs, const float* __restrict__ Wd,
    const float* __restrict__ bd, float* __restrict__ out)
{
    __shared__ __align__(16) float hT[H_DIM * 16];   // hT[k*16 + r]
    __shared__ float lp[16][K_MIX];

    const int tid = threadIdx.x;
    const long row0 = (long)blockIdx.x * 16;

    for (int idx = tid; idx < H_DIM * 16; idx += 256) {
        int r = idx >> 8;
        int k = idx & (H_DIM - 1);
        unsigned int u = outputs[(row0 + r) * H_DIM + k];
        hT[k * 16 + r] = __uint_as_float(u << 16);
    }
    __syncthreads();

    const int  cA = tid;
    const int  cB = tid + 256;
    const bool vB = (cB < MDN_D);
    const float bA = bd[cA];
    const float bB = vB ? bd[cB] : 0.0f;
    float accA[16], accB[16];
    #pragma unroll
    for (int r = 0; r < 16; ++r) { accA[r] = bA; accB[r] = bB; }

    for (int k = 0; k < H_DIM; ++k) {
        float wA = Wd[(size_t)k * MDN_D + cA];
        float wB = vB ? Wd[(size_t)k * MDN_D + cB] : 0.0f;
        const float4* hp = (const float4*)(hT + k * 16);
        float4 h0 = hp[0], h1 = hp[1], h2 = hp[2], h3 = hp[3];
        float hr[16] = { h0.x,h0.y,h0.z,h0.w, h1.x,h1.y,h1.z,h1.w,
                         h2.x,h2.y,h2.z,h2.w, h3.x,h3.y,h3.z,h3.w };
        #pragma unroll
        for (int r = 0; r < 16; ++r) {
            accA[r] = fmaf(hr[r], wA, accA[r]);
            accB[r] = fmaf(hr[r], wB, accB[r]);
        }
    }

    float* out_mu = out + OFF_MU;
    float* out_sg = out + OFF_SIGMA;
    #pragma unroll
    for (int r = 0; r < 16; ++r) {
        long row = row0 + r;
        float v = accA[r];
        if (cA < K_MIX)            lp[r][cA] = v;
        else if (cA < K_MIX + 160) out_mu[row * 160 + (cA - K_MIX)] = v;
        else                       out_sg[row * 160 + (cA - 165)]   = __expf(v) + 1e-6f;
        if (vB)                    out_sg[row * 160 + (cB - 165)]   = __expf(accB[r]) + 1e-6f;
    }
    __syncthreads();

    if (tid < 16) {
        int r = tid;
        long row = row0 + r;
        float v0 = lp[r][0], v1 = lp[r][1], v2 = lp[r][2], v3 = lp[r][3], v4 = lp[r][4];
        float m = fmaxf(fmaxf(fmaxf(v0, v1), fmaxf(v2, v3)), v4);
        float sum = __expf(v0-m) + __expf(v1-m) + __expf(v2-m) + __expf(v3-m) + __expf(v4-m);
        float ls = m + __logf(sum);
        out[row*5 + 0] = v0 - ls;
        out[row*5 + 1] = v1 - ls;
        out[row*5 + 2] = v2 - ls;
        out[row*5 + 3] = v3 - ls;
        out[row*5 + 4] = v4 - ls;
    }
}

extern "C" void kernel_launch(void* const* d_in, const int* in_sizes, int n_in,
                              void* d_out, int out_size, void* d_ws, size_t ws_size,
                              hipStream_t stream)
{
    const float* z_t = (const float*)d_in[0];
    const float* a_t = (const float*)d_in[1];
    const float* Wx  = (const float*)d_in[2];
    const float* Wh  = (const float*)d_in[3];
    const float* b   = (const float*)d_in[4];
    const float* Wd  = (const float*)d_in[5];
    const float* bd  = (const float*)d_in[6];
    float* out = (float*)d_out;

    char* ws = (char*)d_ws;
    __hip_bfloat16* outs = (__hip_bfloat16*)(ws + WS_OUT);
    float* h_glb         = (float*)(ws + WS_HG);

    lstm5_kernel<<<NGRP * NSLICE, 512, 0, stream>>>(z_t, a_t, Wx, Wh, b,
                                                    h_glb, outs,
                                                    out + OFF_C, out + OFF_H);
    mdn_kernel<<<(B_SZ * T_LEN) / 16, 256, 0, stream>>>((const unsigned short*)outs,
                                                        Wd, bd, out);
}

// Round 6
// 1192.194 us; speedup vs baseline: 6.6032x; 1.0116x over previous
//
#include <hip/hip_runtime.h>
#include <hip/hip_bf16.h>
#include <math.h>

// MDN-RNN: B=128, T=512, Z=32, A=3, H=256, K=5, IN=35, 4H=1024, MDN=325
#define T_LEN 512
#define B_SZ  128
#define H_DIM 256
#define G_DIM 1024
#define IN_D  35
#define MDN_D 325
#define K_MIX 5

#define NSLICE 4     // gate-dim slices per group (each owns 64 h-cols x 4 gates)
#define BG     2     // batches per group
#define NGRP   64    // 128 / BG   -> 256 blocks total = 1/CU

// d_out layout: log_pi[B,T,5] | mu[B,T,5,32] | sigma[B,T,5,32] | c[B,256] | h[B,256]
static constexpr long OFF_MU    = 327680L;
static constexpr long OFF_SIGMA = 10813440L;
static constexpr long OFF_C     = 21299200L;
static constexpr long OFF_H     = 21331968L;

// ws layout (~34 MB; ws >= 64 MiB proven in round 1)
static constexpr size_t WS_OUT = 0;          // bf16 outs: B*T*H*2 = 33,554,432 B
static constexpr size_t WS_HG  = 33554432;   // 64 grp * 2 par * 2 b * 256 f32 = 512 KB

typedef unsigned uint2v  __attribute__((ext_vector_type(2)));
typedef float    float2v __attribute__((ext_vector_type(2)));
typedef float    float4v __attribute__((ext_vector_type(4)));

__device__ __forceinline__ float fast_sigmoid(float x) { return 1.0f / (1.0f + __expf(-x)); }
__device__ __forceinline__ float fast_tanh(float x) {
    return 1.0f - 2.0f / (__expf(2.0f * x) + 1.0f);
}

// acc.lo += w.lo*h.lo ; acc.hi += w.hi*h.lo   (broadcast LOW half of h-pair)
__device__ __forceinline__ void pk_fma_lo(float2v& acc, float2v w, float2v h) {
    asm("v_pk_fma_f32 %0, %1, %2, %0 op_sel:[0,0,0] op_sel_hi:[1,0,1]"
        : "+v"(acc) : "v"(w), "v"(h));
}
// acc.lo += w.lo*h.hi ; acc.hi += w.hi*h.hi   (broadcast HIGH half of h-pair)
__device__ __forceinline__ void pk_fma_hi(float2v& acc, float2v w, float2v h) {
    asm("v_pk_fma_f32 %0, %1, %2, %0 op_sel:[0,1,0] op_sel_hi:[1,1,1]"
        : "+v"(acc) : "v"(w), "v"(h));
}

// 256 blocks (group=bid&63, slice=bid>>6), 512 threads.
// Weights VGPR-resident, PINNED via opaque asm (defeats per-step rematerialization
// of the global loads, which was costing ~300 KB/step/CU of L2 traffic in r4/r5).
// Inner loop = v_pk_fma_f32 (dual fp32 FMA), columns paired, h broadcast via op_sel.
// h exchange: self-validating dwords (h in (-1,1); low 2 mantissa bits = t&3);
// waves 0-1 write+publish, waves 2-4 poll foreign dwords, wave 6 stages x(t+1).
__global__ __launch_bounds__(512, 1) void lstm6_kernel(
    const float* __restrict__ z_t, const float* __restrict__ a_t,
    const float* __restrict__ Wx,  const float* __restrict__ Wh,
    const float* __restrict__ bias,
    float* __restrict__ h_glb,
    __hip_bfloat16* __restrict__ outs,
    float* __restrict__ out_c, float* __restrict__ out_h)
{
    const int bid = blockIdx.x;
    const int gr  = bid & 63;
    const int s   = bid >> 6;
    const int tid = threadIdx.x;
    const int cg  = tid >> 2;              // cols {2cg, 2cg+1} of this 256-col slice
    const int kq  = tid & 3;               // k-range [kq*64, kq*64+64)
    const int lc0 = cg * 2;
    const int gate = lc0 >> 6;
    const int j0   = lc0 & 63;
    const int gcol0 = gate * 256 + s * 64 + j0;

    __shared__ __align__(16) float h_lds[BG][4][68];   // kq sections padded (+4)
    __shared__ __align__(16) float x_lds[BG][44];      // 40 used (4x10 k-split), pad 0
    __shared__ __align__(16) float g_red[BG][256];

    for (int i = tid; i < BG * 4 * 68; i += 512) ((float*)h_lds)[i] = 0.0f;  // h(-1)=0
    if (tid < BG * 9) { int b = tid / 9, k = tid - 9 * b; x_lds[b][35 + k] = 0.0f; }

    // ---- persistent weights in VGPRs: load once, then PIN (no remat possible) ----
    float2v W2[64];
    #pragma unroll
    for (int i = 0; i < 64; ++i) {
        const size_t r = (size_t)(kq * 64 + i) * G_DIM;
        W2[i].x = Wh[r + gcol0];
        W2[i].y = Wh[r + gcol0 + 1];
    }
    float2v X2[10];
    #pragma unroll
    for (int i = 0; i < 10; ++i) {
        int xk = kq * 10 + i;
        bool ok = (xk < IN_D);
        X2[i].x = ok ? Wx[(size_t)xk * G_DIM + gcol0]     : 0.0f;
        X2[i].y = ok ? Wx[(size_t)xk * G_DIM + gcol0 + 1] : 0.0f;
    }
    #pragma unroll
    for (int i = 0; i < 64; ++i) asm volatile("" : "+v"(W2[i]));
    #pragma unroll
    for (int i = 0; i < 10; ++i) asm volatile("" : "+v"(X2[i]));

    // writer role (tid<128): batch cb, h-col cj of this slice
    const int cb = tid >> 6;
    const int cj = tid & 63;
    const float bc0 = bias[0 * 256 + s * 64 + cj];
    const float bc1 = bias[1 * 256 + s * 64 + cj];
    const float bc2 = bias[2 * 256 + s * 64 + cj];
    const float bc3 = bias[3 * 256 + s * 64 + cj];
    float c_reg = 0.0f;

    // poller role (tid in [128,320)): q -> foreign dword pair (b, kk)
    const int q  = tid - 128;              // 0..191
    const int pb = (q >= 96) ? 1 : 0;
    const int pp = q - 96 * pb;            // 0..95
    const int pk0 = pp * 2;
    const int pkk = pk0 + ((pk0 >= s * 64) ? 64 : 0);   // skip own slice's 64-chunk

    const int batch0 = gr * BG;
    float* hg = h_glb + (size_t)gr * (2 * BG * H_DIM);   // [2][BG][256]

    // ---- pre-loop: stage x(0) ----
    if (tid >= 384 && tid < 448) {
        int qq = tid - 384, b = qq >> 5, k = qq & 31;
        x_lds[b][k] = z_t[((size_t)(batch0 + b) * T_LEN + 0) * 32 + k];
    } else if (tid >= 448 && tid < 448 + BG * 3) {
        int qq = tid - 448, b = (qq >= 3), k = qq - 3 * b;
        x_lds[b][32 + k] = a_t[((size_t)(batch0 + b) * T_LEN + 0) * 3 + k];
    }
    __syncthreads();

    for (int t = 0; t < T_LEN; ++t) {
        // ---- (A) pollers fetch foreign h(t-1): self-validating dword pairs ----
        if (t > 0 && tid >= 128 && tid < 320) {
            const unsigned want = (unsigned)((t - 1) & 3);
            const float* ap = hg + ((t - 1) & 1) * (BG * H_DIM) + pb * H_DIM + pkk;
            uint2v u;
            do {
                asm volatile("global_load_dwordx2 %0, %1, off sc0 sc1\n\t"
                             "s_waitcnt vmcnt(0)"
                             : "=v"(u) : "v"(ap) : "memory");
            } while ((u.x & 3u) != want || (u.y & 3u) != want);
            float* dst = &h_lds[pb][pkk >> 6][pkk & 63];
            dst[0] = __uint_as_float(u.x);
            dst[1] = __uint_as_float(u.y);
        }
        __syncthreads();   // B1: h_lds + x_lds(t) ready

        // ---- (B) packed FMA: 2 batches x col-pair x 64 k per thread ----
        float2v acc0 = {0.0f, 0.0f}, acc1 = {0.0f, 0.0f};
        {
            const float4v* hp0 = (const float4v*)h_lds[0][kq];
            const float4v* hp1 = (const float4v*)h_lds[1][kq];
            #pragma unroll
            for (int i4 = 0; i4 < 16; ++i4) {
                float4v hv0 = hp0[i4];
                float4v hv1 = hp1[i4];
                float2v h0lo = __builtin_shufflevector(hv0, hv0, 0, 1);
                float2v h0hi = __builtin_shufflevector(hv0, hv0, 2, 3);
                float2v h1lo = __builtin_shufflevector(hv1, hv1, 0, 1);
                float2v h1hi = __builtin_shufflevector(hv1, hv1, 2, 3);
                pk_fma_lo(acc0, W2[4*i4+0], h0lo); pk_fma_lo(acc1, W2[4*i4+0], h1lo);
                pk_fma_hi(acc0, W2[4*i4+1], h0lo); pk_fma_hi(acc1, W2[4*i4+1], h1lo);
                pk_fma_lo(acc0, W2[4*i4+2], h0hi); pk_fma_lo(acc1, W2[4*i4+2], h1hi);
                pk_fma_hi(acc0, W2[4*i4+3], h0hi); pk_fma_hi(acc1, W2[4*i4+3], h1hi);
            }
            #pragma unroll
            for (int i = 0; i < 5; ++i) {
                float2v xv0 = *(const float2v*)&x_lds[0][kq * 10 + 2 * i];
                float2v xv1 = *(const float2v*)&x_lds[1][kq * 10 + 2 * i];
                pk_fma_lo(acc0, X2[2*i],   xv0); pk_fma_lo(acc1, X2[2*i],   xv1);
                pk_fma_hi(acc0, X2[2*i+1], xv0); pk_fma_hi(acc1, X2[2*i+1], xv1);
            }
        }
        float a00 = acc0.x, a01 = acc0.y, a10 = acc1.x, a11 = acc1.y;
        // k-reduce across the 4 kq lanes of each quad
        a00 += __shfl_xor(a00, 1, 64); a00 += __shfl_xor(a00, 2, 64);
        a01 += __shfl_xor(a01, 1, 64); a01 += __shfl_xor(a01, 2, 64);
        a10 += __shfl_xor(a10, 1, 64); a10 += __shfl_xor(a10, 2, 64);
        a11 += __shfl_xor(a11, 1, 64); a11 += __shfl_xor(a11, 2, 64);
        if (kq == 0) {
            g_red[0][lc0] = a00; g_red[0][lc0 + 1] = a01;
            g_red[1][lc0] = a10; g_red[1][lc0 + 1] = a11;
        }
        __syncthreads();   // B2: g_red ready; FMA reads of h_lds/x_lds done

        // ---- (C) writers: nonlin + c/h update + tagged publish + local h_lds ----
        if (tid < 128) {
            float gi = g_red[cb][      cj] + bc0;
            float gf = g_red[cb][ 64 + cj] + bc1;
            float gg = g_red[cb][128 + cj] + bc2;
            float go = g_red[cb][192 + cj] + bc3;
            float iv = fast_sigmoid(gi), fv = fast_sigmoid(gf), ov = fast_sigmoid(go);
            float gv = fast_tanh(gg);
            c_reg = fmaf(fv, c_reg, iv * gv);
            float hv = ov * fast_tanh(c_reg);
            unsigned u = (__float_as_uint(hv) & ~3u) | (unsigned)(t & 3);
            float* dst = hg + (t & 1) * (BG * H_DIM) + cb * H_DIM + s * 64 + cj;
            asm volatile("global_store_dword %0, %1, off sc0 sc1"
                         :: "v"(dst), "v"(u) : "memory");
            h_lds[cb][s][cj] = __uint_as_float(u);   // own slice: no IC round trip
            outs[((size_t)(batch0 + cb) * T_LEN + t) * H_DIM + s * 64 + cj] =
                __float2bfloat16(hv);
            if (t == T_LEN - 1) {
                out_c[(batch0 + cb) * H_DIM + s * 64 + cj] = c_reg;
                out_h[(batch0 + cb) * H_DIM + s * 64 + cj] = hv;
            }
        }
        // ---- (C) stagers: x(t+1) -> x_lds (FMA readers are already past B2) ----
        if (t + 1 < T_LEN) {
            if (tid >= 384 && tid < 448) {
                int qq = tid - 384, b = qq >> 5, k = qq & 31;
                x_lds[b][k] = z_t[((size_t)(batch0 + b) * T_LEN + (t + 1)) * 32 + k];
            } else if (tid >= 448 && tid < 448 + BG * 3) {
                int qq = tid - 448, b = (qq >= 3), k = qq - 3 * b;
                x_lds[b][32 + k] = a_t[((size_t)(batch0 + b) * T_LEN + (t + 1)) * 3 + k];
            }
        }
        // next iteration's B1 orders all LDS writes; pollers gate on foreign stores
    }
}

// mdn = outputs(bf16) @ Wd + bd, fused log_softmax(log_pi) and exp(log_sigma)+1e-6.
__global__ __launch_bounds__(256, 1) void mdn_kernel(
    const unsigned short* __restrict__ outputs, const float* __restrict__ Wd,
    const float* __restrict__ bd, float* __restrict__ out)
{
    __shared__ __align__(16) float hT[H_DIM * 16];   // hT[k*16 + r]
    __shared__ float lp[16][K_MIX];

    const int tid = threadIdx.x;
    const long row0 = (long)blockIdx.x * 16;

    for (int idx = tid; idx < H_DIM * 16; idx += 256) {
        int r = idx >> 8;
        int k = idx & (H_DIM - 1);
        unsigned int u = outputs[(row0 + r) * H_DIM + k];
        hT[k * 16 + r] = __uint_as_float(u << 16);
    }
    __syncthreads();

    const int  cA = tid;
    const int  cB = tid + 256;
    const bool vB = (cB < MDN_D);
    const float bA = bd[cA];
    const float bB = vB ? bd[cB] : 0.0f;
    float accA[16], accB[16];
    #pragma unroll
    for (int r = 0; r < 16; ++r) { accA[r] = bA; accB[r] = bB; }

    for (int k = 0; k < H_DIM; ++k) {
        float wA = Wd[(size_t)k * MDN_D + cA];
        float wB = vB ? Wd[(size_t)k * MDN_D + cB] : 0.0f;
        const float4* hp = (const float4*)(hT + k * 16);
        float4 h0 = hp[0], h1 = hp[1], h2 = hp[2], h3 = hp[3];
        float hr[16] = { h0.x,h0.y,h0.z,h0.w, h1.x,h1.y,h1.z,h1.w,
                         h2.x,h2.y,h2.z,h2.w, h3.x,h3.y,h3.z,h3.w };
        #pragma unroll
        for (int r = 0; r < 16; ++r) {
            accA[r] = fmaf(hr[r], wA, accA[r]);
            accB[r] = fmaf(hr[r], wB, accB[r]);
        }
    }

    float* out_mu = out + OFF_MU;
    float* out_sg = out + OFF_SIGMA;
    #pragma unroll
    for (int r = 0; r < 16; ++r) {
        long row = row0 + r;
        float v = accA[r];
        if (cA < K_MIX)            lp[r][cA] = v;
        else if (cA < K_MIX + 160) out_mu[row * 160 + (cA - K_MIX)] = v;
        else                       out_sg[row * 160 + (cA - 165)]   = __expf(v) + 1e-6f;
        if (vB)                    out_sg[row * 160 + (cB - 165)]   = __expf(accB[r]) + 1e-6f;
    }
    __syncthreads();

    if (tid < 16) {
        int r = tid;
        long row = row0 + r;
        float v0 = lp[r][0], v1 = lp[r][1], v2 = lp[r][2], v3 = lp[r][3], v4 = lp[r][4];
        float m = fmaxf(fmaxf(fmaxf(v0, v1), fmaxf(v2, v3)), v4);
        float sum = __expf(v0-m) + __expf(v1-m) + __expf(v2-m) + __expf(v3-m) + __expf(v4-m);
        float ls = m + __logf(sum);
        out[row*5 + 0] = v0 - ls;
        out[row*5 + 1] = v1 - ls;
        out[row*5 + 2] = v2 - ls;
        out[row*5 + 3] = v3 - ls;
        out[row*5 + 4] = v4 - ls;
    }
}

extern "C" void kernel_launch(void* const* d_in, const int* in_sizes, int n_in,
                              void* d_out, int out_size, void* d_ws, size_t ws_size,
                              hipStream_t stream)
{
    const float* z_t = (const float*)d_in[0];
    const float* a_t = (const float*)d_in[1];
    const float* Wx  = (const float*)d_in[2];
    const float* Wh  = (const float*)d_in[3];
    const float* b   = (const float*)d_in[4];
    const float* Wd  = (const float*)d_in[5];
    const float* bd  = (const float*)d_in[6];
    float* out = (float*)d_out;

    char* ws = (char*)d_ws;
    __hip_bfloat16* outs = (__hip_bfloat16*)(ws + WS_OUT);
    float* h_glb         = (float*)(ws + WS_HG);

    lstm6_kernel<<<NGRP * NSLICE, 512, 0, stream>>>(z_t, a_t, Wx, Wh, b,
                                                    h_glb, outs,
                                                    out + OFF_C, out + OFF_H);
    mdn_kernel<<<(B_SZ * T_LEN) / 16, 256, 0, stream>>>((const unsigned short*)outs,
                                                        Wd, bd, out);
}